// Round 13
// baseline (106.249 us; speedup 1.0000x reference)
//
#include <hip/hip_runtime.h>
#include <hip/hip_fp16.h>

// Deformable Conv2d — MI355X, round 13
// vs round 11/12: (1) tile-interleaved issue/finish pipeline — both tiles'
// 8 corner ds_read_b128 issue before either blend, so LDS latency hides
// under blend VALU and the two pipes overlap instead of ping-ponging;
// (2) zero-staging: out-of-image window slots hold 0.0, making w*valid*v
// automatic -> fast-path predicate is 2 unsigned compares, no clamps,
// no validity cndmasks; (3) lane-constant py/px bases hoisted.

#define KSZ 3
#define PAD 1

static constexpr int B   = 4;
static constexpr int Cin = 64;
static constexpr int H   = 256;
static constexpr int W   = 256;
static constexpr int G   = 8;
static constexpr int OC  = 64;
static constexpr int KK  = KSZ * KSZ;  // 9
static constexpr int Cpg = Cin / G;    // 8
static constexpr int OPG = OC / G;     // 8
static constexpr int HW  = H * W;
static constexpr int NXCD = 8;

static constexpr int BR    = 4;        // output rows per block
static constexpr int BC    = 64;       // output cols per block
static constexpr int MARG  = 5;
static constexpr int WROWS = BR + 2 * MARG + 1;  // 15
static constexpr int WCOLS = 75;                 // 74 used + 1 spare
static constexpr int WUSED = BC + 2 * MARG;      // 74

typedef _Float16 f16x8  __attribute__((ext_vector_type(8)));
typedef float    f32x16 __attribute__((ext_vector_type(16)));

union U4H {
    uint4 u;
    __half2 h2[4];
    _Float16 h[8];
    f16x8 v;
};

struct Pend {
    float wy, wx, ms;
    int   iy0, ix0;
    bool  ok;
    uint4 c00, c01, c10, c11;
};

// ---- transpose: x [B,Cin,H,W] f32 -> xt [B,G,H,W,Cpg] fp16 (16B/pixel) ----
__global__ __launch_bounds__(256) void transpose_kernel(
    const float* __restrict__ x, uint4* __restrict__ xt)
{
    const int h = blockIdx.x, g = blockIdx.y, b = blockIdx.z;
    const int w = threadIdx.x;
    const int pix = h * W + w;
    const float* src = x + (size_t)(b * Cin + g * Cpg) * HW + pix;
    U4H v;
#pragma unroll
    for (int c = 0; c < 8; ++c) v.h[c] = (_Float16)src[(size_t)c * HW];
    xt[(size_t)(b * G + g) * HW + pix] = v.u;
}

// ---- prep: per-lane MFMA A-fragments, layout [g][m][lane] (40 KB) ----
__global__ __launch_bounds__(320) void prep_weights(
    const float* __restrict__ weight, uint4* __restrict__ wfrag)
{
    const int g    = blockIdx.x;
    const int tid  = threadIdx.x;     // 0..319
    const int m    = tid >> 6;        // 0..4
    const int lane = tid & 63;
    const int hi   = lane >> 5;
    const int lp   = lane & 31;
    const int t    = 2 * m + hi;
    U4H a;
#pragma unroll
    for (int c = 0; c < 8; ++c) {
        float v = 0.0f;
        if (lp < OPG && t < KK)
            v = weight[((size_t)(g * OPG + lp) * Cpg + c) * KK + t];
        a.h[c] = (_Float16)v;
    }
    wfrag[((size_t)g * 5 + m) * 64 + lane] = a.u;
}

// ---- main kernel: 256 threads, 4 rows x 64 cols per block ----
__global__ __launch_bounds__(256) void dcn_kernel(
    const uint4* __restrict__ xt,
    const uint4* __restrict__ wfrag,
    const float* __restrict__ offset,
    const float* __restrict__ mask,
    const float* __restrict__ bias,
    float* __restrict__ out)
{
    __shared__ uint4 win[WROWS * WCOLS];   // 18,000 B

    // XCD-chunked bijective swizzle (8192 blocks % 8 == 0)
    const unsigned id = blockIdx.x;
    const unsigned wl = (id & (NXCD - 1)) * (gridDim.x / NXCD) + (id >> 3);
    const int colblk = wl & 3;                // 0..3
    const int rowblk = (wl >> 2) & 63;        // 0..63
    const int g      = (wl >> 8) & (G - 1);
    const int b      = wl >> 11;

    const int h_base = rowblk * BR;
    const int xbase  = colblk * BC;
    const int h0     = h_base - MARG;
    const int x0base = xbase - MARG;

    const int tid  = threadIdx.x;
    const int lane = tid & 63;
    const int wave = tid >> 6;                // 0..3 -> output row
    const int hi   = lane >> 5;               // tap parity in MFMA k dim
    const int lp   = lane & 31;               // A-row (out ch) / B-col (pixel)

    const int h = h_base + wave;

    const uint4* xb = xt + (size_t)(b * G + g) * HW;

    // ---- stage the 15x74 window; out-of-image slots get ZERO ----
#pragma unroll
    for (int it = 0; it < 5; ++it) {
        const int k = it * 256 + tid;
        if (k < WROWS * WCOLS) {
            const int i = k / WCOLS;
            const int j = k - i * WCOLS;
            const int gr = h0 + i;
            const int gc = x0base + j;
            const bool vld = ((unsigned)gr < (unsigned)H) & ((unsigned)gc < (unsigned)W);
            const int grc = min(max(gr, 0), H - 1);
            const int gcc = min(max(gc, 0), W - 1);
            uint4 val = xb[grc * W + gcc];
            if (!vld) val = make_uint4(0, 0, 0, 0);
            win[k] = val;
        }
    }

    // A-fragments: 5 coalesced dwordx4 loads (precomputed by prep_weights)
    f16x8 afrag[5];
    {
        const uint4* wf = wfrag + (size_t)g * 5 * 64 + lane;
#pragma unroll
        for (int m = 0; m < 5; ++m) {
            U4H tmp; tmp.u = wf[m * 64];
            afrag[m] = tmp.v;
        }
    }

    const float* offy = offset + (size_t)(b * 2 + 0) * (G * KK) * HW;
    const float* offx = offset + (size_t)(b * 2 + 1) * (G * KK) * HW;
    const float* mk   = mask + (size_t)b * (G * KK) * HW;

    // burst all offset/mask loads (sigmoid + tap-9 pad folded here)
    float dyv[2][5], dxv[2][5], msv[2][5];
#pragma unroll
    for (int tile = 0; tile < 2; ++tile) {
        const int wq  = xbase + tile * 32 + lp;
        const int pix = h * W + wq;
#pragma unroll
        for (int m = 0; m < 5; ++m) {
            const int t  = 2 * m + hi;
            const int tt = (t > 8) ? 8 : t;
            const int idx0 = G * KK - 1 - (g * KK + tt);   // flipped tap axis
            dyv[tile][m] = offy[(size_t)idx0 * HW + pix];
            dxv[tile][m] = offx[(size_t)idx0 * HW + pix];
            const float mv = mk[(size_t)(g * KK + tt) * HW + pix];
            float s = 1.0f / (1.0f + __expf(-mv));
            msv[tile][m] = (t <= 8) ? s : 0.0f;
        }
    }

    // lane-constant sample-position bases (hoists ki/kj integer math)
    float pyb[5], pxb0[5], pxb1[5];
#pragma unroll
    for (int m = 0; m < 5; ++m) {
        const int t  = 2 * m + hi;
        const int tt = (t > 8) ? 8 : t;
        const int ki = (tt >= 3) + (tt >= 6);
        const int kj = tt - 3 * ki;
        pyb[m]  = (float)(h - PAD + ki);
        pxb0[m] = (float)(xbase + lp - PAD + kj);
        pxb1[m] = pxb0[m] + 32.0f;
    }

    __syncthreads();   // window ready

    // issue: address math + 4 window reads (no clamps, 2-compare predicate)
    auto issue = [&](float pybm, float pxbm, float dy, float dx, float ms) -> Pend {
        Pend p;
        const float py = pybm + dy;
        const float px = pxbm + dx;
        const float y0f = floorf(py), x0f = floorf(px);
        p.wy = py - y0f;
        p.wx = px - x0f;
        p.ms = ms;
        p.iy0 = (int)y0f - h0;
        p.ix0 = (int)x0f - x0base;
        p.ok = ((unsigned)p.iy0 <= (unsigned)(WROWS - 2)) &
               ((unsigned)p.ix0 <= (unsigned)(WUSED - 2));
        int a0 = p.iy0 * WCOLS + p.ix0;
        a0 = p.ok ? a0 : 0;
        p.c00 = win[a0];         p.c01 = win[a0 + 1];
        p.c10 = win[a0 + WCOLS]; p.c11 = win[a0 + WCOLS + 1];
        return p;
    };

    // finish: weights + rare slow path + blend
    auto finish = [&](Pend p) -> f16x8 {
        const float u  = (1.f - p.wy) * p.ms;
        const float vv = p.wy * p.ms;
        const float cx0 = 1.f - p.wx, cx1 = p.wx;
        float w00 = u * cx0, w01 = u * cx1, w10 = vv * cx0, w11 = vv * cx1;
        if (__builtin_expect(!__all((int)p.ok), 0)) {   // |offset| > ~4.5
            if (!p.ok) {
                const int y0 = p.iy0 + h0, x0 = p.ix0 + x0base;
                const bool vy0 = (y0 >= 0) & (y0 < H), vy1 = (y0 + 1 >= 0) & (y0 + 1 < H);
                const bool vx0 = (x0 >= 0) & (x0 < W), vx1 = (x0 + 1 >= 0) & (x0 + 1 < W);
                const float uu = vy0 ? u : 0.f,  vz = vy1 ? vv : 0.f;
                const float ca = vx0 ? cx0 : 0.f, cb = vx1 ? cx1 : 0.f;
                w00 = uu * ca; w01 = uu * cb; w10 = vz * ca; w11 = vz * cb;
                const int yc0 = min(max(y0, 0), H - 1), yc1 = min(max(y0 + 1, 0), H - 1);
                const int xc0 = min(max(x0, 0), W - 1), xc1 = min(max(x0 + 1, 0), W - 1);
                p.c00 = xb[yc0 * W + xc0]; p.c01 = xb[yc0 * W + xc1];
                p.c10 = xb[yc1 * W + xc0]; p.c11 = xb[yc1 * W + xc1];
            }
        }
        U4H a, bq, c, d; a.u = p.c00; bq.u = p.c01; c.u = p.c10; d.u = p.c11;
        const __half2 h00 = __float2half2_rn(w00);
        const __half2 h01 = __float2half2_rn(w01);
        const __half2 h10 = __float2half2_rn(w10);
        const __half2 h11 = __float2half2_rn(w11);
        U4H s;
#pragma unroll
        for (int i = 0; i < 4; ++i)
            s.h2[i] = __hfma2(h00, a.h2[i],
                      __hfma2(h01, bq.h2[i],
                      __hfma2(h10, c.h2[i],
                      __hmul2(h11, d.h2[i]))));
        return s.v;
    };

    f32x16 acc0 = {};
    f32x16 acc1 = {};
#pragma unroll
    for (int m = 0; m < 5; ++m) {
        // issue both tiles' 8 reads, then blend both: LDS latency hides
        // under blend VALU; LDS and VALU pipes overlap.
        Pend p0 = issue(pyb[m], pxb0[m], dyv[0][m], dxv[0][m], msv[0][m]);
        Pend p1 = issue(pyb[m], pxb1[m], dyv[1][m], dxv[1][m], msv[1][m]);
        acc0 = __builtin_amdgcn_mfma_f32_32x32x16_f16(afrag[m], finish(p0), acc0, 0, 0, 0);
        acc1 = __builtin_amdgcn_mfma_f32_32x32x16_f16(afrag[m], finish(p1), acc1, 0, 0, 0);
    }

    // C layout: col = lp (pixel), row = (reg&3) + 8*(reg>>2) + 4*hi.
    // Useful rows 0..7 -> out channel d = reg + 4*hi (regs 0..3).
#pragma unroll
    for (int tile = 0; tile < 2; ++tile) {
        const int wq = xbase + tile * 32 + lp;
#pragma unroll
        for (int r = 0; r < 4; ++r) {
            const int dd = r + 4 * hi;
            const float v = (tile == 0 ? acc0[r] : acc1[r]) + bias[g * OPG + dd];
            out[((size_t)b * OC + g * OPG + dd) * HW + h * W + wq] = v;
        }
    }
}

extern "C" void kernel_launch(void* const* d_in, const int* in_sizes, int n_in,
                              void* d_out, int out_size, void* d_ws, size_t ws_size,
                              hipStream_t stream) {
    const float* x      = (const float*)d_in[0];
    const float* offset = (const float*)d_in[1];
    const float* mask   = (const float*)d_in[2];
    const float* weight = (const float*)d_in[3];
    const float* bias   = (const float*)d_in[4];
    float* out = (float*)d_out;

    uint4* xt    = (uint4*)d_ws;                                      // 32 MiB
    uint4* wfrag = (uint4*)((char*)d_ws + (size_t)B * G * HW * 16);   // 40 KiB

    dim3 tgrid(H, G, B);
    transpose_kernel<<<tgrid, dim3(256), 0, stream>>>(x, xt);
    prep_weights<<<dim3(G), dim3(320), 0, stream>>>(weight, wfrag);
    dcn_kernel<<<dim3(B * G * (H / BR) * (W / BC)), dim3(256), 0, stream>>>(
        xt, wfrag, offset, mask, bias, out);
}

// Round 14
// 96.619 us; speedup vs baseline: 1.0997x; 1.0997x over previous
//
#include <hip/hip_runtime.h>
#include <hip/hip_fp16.h>

// Deformable Conv2d — MI355X, round 14
// vs R11/R13: persistent-style blocks. Grid 2048 (~8 blocks/CU resident for
// the whole kernel), each block loops over 4 vertically-adjacent 4x64 tiles
// with a 16-row RING window (slot = y&15, 19.2 KB): 12/16 rows carry over,
// only 4 rows restaged per step (issued to regs before compute, written to
// LDS after a barrier -> latency hidden). Tests the "short-block residency
// cap" theory that explains occupancy pinning at ~30% while static limits
// allow 8 blocks/CU.

#define KSZ 3
#define PAD 1

static constexpr int B   = 4;
static constexpr int Cin = 64;
static constexpr int H   = 256;
static constexpr int W   = 256;
static constexpr int G   = 8;
static constexpr int OC  = 64;
static constexpr int KK  = KSZ * KSZ;  // 9
static constexpr int Cpg = Cin / G;    // 8
static constexpr int OPG = OC / G;     // 8
static constexpr int HW  = H * W;
static constexpr int NXCD = 8;

static constexpr int BR    = 4;        // output rows per tile
static constexpr int TPB   = 4;        // tiles per block (16 rows)
static constexpr int BC    = 64;       // output cols per tile
static constexpr int WRING = 16;       // ring rows (y & 15)
static constexpr int WCOLS = 75;       // 16B slots per ring row (74 used + 1)
static constexpr int WUSED = 74;

typedef _Float16 f16x8  __attribute__((ext_vector_type(8)));
typedef float    f32x16 __attribute__((ext_vector_type(16)));

union U4H {
    uint4 u;
    __half2 h2[4];
    _Float16 h[8];
    f16x8 v;
};

// ---- transpose: x [B,Cin,H,W] f32 -> xt [B,G,H,W,Cpg] fp16 (16B/pixel) ----
__global__ __launch_bounds__(256) void transpose_kernel(
    const float* __restrict__ x, uint4* __restrict__ xt)
{
    const int h = blockIdx.x, g = blockIdx.y, b = blockIdx.z;
    const int w = threadIdx.x;
    const int pix = h * W + w;
    const float* src = x + (size_t)(b * Cin + g * Cpg) * HW + pix;
    U4H v;
#pragma unroll
    for (int c = 0; c < 8; ++c) v.h[c] = (_Float16)src[(size_t)c * HW];
    xt[(size_t)(b * G + g) * HW + pix] = v.u;
}

// ---- prep: per-lane MFMA A-fragments, layout [g][m][lane] (40 KB) ----
__global__ __launch_bounds__(320) void prep_weights(
    const float* __restrict__ weight, uint4* __restrict__ wfrag)
{
    const int g    = blockIdx.x;
    const int tid  = threadIdx.x;     // 0..319
    const int m    = tid >> 6;        // 0..4
    const int lane = tid & 63;
    const int hi   = lane >> 5;
    const int lp   = lane & 31;
    const int t    = 2 * m + hi;
    U4H a;
#pragma unroll
    for (int c = 0; c < 8; ++c) {
        float v = 0.0f;
        if (lp < OPG && t < KK)
            v = weight[((size_t)(g * OPG + lp) * Cpg + c) * KK + t];
        a.h[c] = (_Float16)v;
    }
    wfrag[((size_t)g * 5 + m) * 64 + lane] = a.u;
}

// ---- main kernel: 256 threads, 4 tiles of 4 rows x 64 cols per block ----
__global__ __launch_bounds__(256) void dcn_kernel(
    const uint4* __restrict__ xt,
    const uint4* __restrict__ wfrag,
    const float* __restrict__ offset,
    const float* __restrict__ mask,
    const float* __restrict__ bias,
    float* __restrict__ out)
{
    __shared__ uint4 win[WRING * WCOLS];   // 19,200 B

    // XCD-chunked bijective swizzle (2048 blocks % 8 == 0)
    const unsigned id = blockIdx.x;
    const unsigned wl = (id & (NXCD - 1)) * (gridDim.x / NXCD) + (id >> 3);
    const int q      = wl & 15;               // row-quad (16 rows)
    const int colblk = (wl >> 4) & 3;
    const int g      = (wl >> 6) & (G - 1);
    const int b      = wl >> 9;

    const int h_start = q * (BR * TPB);       // first output row
    const int xbase   = colblk * BC;
    const int x0base  = xbase - 5;

    const int tid  = threadIdx.x;
    const int lane = tid & 63;
    const int wave = tid >> 6;                // 0..3 -> row within tile
    const int hi   = lane >> 5;               // tap parity in MFMA k dim
    const int lp   = lane & 31;               // A-row (out ch) / B-col (pixel)

    const uint4* xb = xt + (size_t)(b * G + g) * HW;

    // ---- initial stage: ring rows h_start-5 .. h_start+10 (zero-staged) ----
#pragma unroll
    for (int it = 0; it < 5; ++it) {
        const int k = it * 256 + tid;
        if (k < WRING * WCOLS) {
            const int i = k / WCOLS;
            const int j = k - i * WCOLS;
            const int y  = h_start - 5 + i;
            const int gc = x0base + j;
            const bool vld = ((unsigned)y < (unsigned)H) & ((unsigned)gc < (unsigned)W);
            const int yc = min(max(y, 0), H - 1);
            const int gcc = min(max(gc, 0), W - 1);
            uint4 val = xb[yc * W + gcc];
            if (!vld) val = make_uint4(0, 0, 0, 0);
            win[(y & 15) * WCOLS + j] = val;
        }
    }

    // A-fragments: 5 coalesced dwordx4 loads (precomputed by prep_weights)
    f16x8 afrag[5];
    {
        const uint4* wf = wfrag + (size_t)g * 5 * 64 + lane;
#pragma unroll
        for (int m = 0; m < 5; ++m) {
            U4H tmp; tmp.u = wf[m * 64];
            afrag[m] = tmp.v;
        }
    }

    const float* offy = offset + (size_t)(b * 2 + 0) * (G * KK) * HW;
    const float* offx = offset + (size_t)(b * 2 + 1) * (G * KK) * HW;
    const float* mk   = mask + (size_t)b * (G * KK) * HW;

    // one tap: bilinear blend of 4 corners from the ring window
    auto sample = [&](int hb5, float py, float px, float ms) -> f16x8 {
        const float y0f = floorf(py), x0f = floorf(px);
        const float wy = py - y0f, wx = px - x0f;
        const int y0  = (int)y0f, x0 = (int)x0f;
        const int ix0 = x0 - x0base;
        const bool ok = ((unsigned)(y0 - hb5) <= 14u) & ((unsigned)ix0 <= 72u);
        int a0 = (y0 & 15) * WCOLS + ix0;
        int a1 = ((y0 + 1) & 15) * WCOLS + ix0;
        a0 = ok ? a0 : 0;
        a1 = ok ? a1 : 0;
        uint4 c00 = win[a0], c01 = win[a0 + 1];
        uint4 c10 = win[a1], c11 = win[a1 + 1];

        const float u  = (1.f - wy) * ms;
        const float vv = wy * ms;
        float w00 = u * (1.f - wx), w01 = u * wx;
        float w10 = vv * (1.f - wx), w11 = vv * wx;

        if (__builtin_expect(!__all((int)ok), 0)) {    // |offset| > ~4
            if (!ok) {
                const bool vy0 = (unsigned)y0 < (unsigned)H;
                const bool vy1 = (unsigned)(y0 + 1) < (unsigned)H;
                const bool vx0 = (unsigned)x0 < (unsigned)W;
                const bool vx1 = (unsigned)(x0 + 1) < (unsigned)W;
                const float uu = vy0 ? u : 0.f,  vz = vy1 ? vv : 0.f;
                const float ca = vx0 ? (1.f - wx) : 0.f;
                const float cb = vx1 ? wx : 0.f;
                w00 = uu * ca; w01 = uu * cb; w10 = vz * ca; w11 = vz * cb;
                const int yc0 = min(max(y0, 0), H - 1), yc1 = min(max(y0 + 1, 0), H - 1);
                const int xc0 = min(max(x0, 0), W - 1), xc1 = min(max(x0 + 1, 0), W - 1);
                c00 = xb[yc0 * W + xc0]; c01 = xb[yc0 * W + xc1];
                c10 = xb[yc1 * W + xc0]; c11 = xb[yc1 * W + xc1];
            }
        }

        U4H a, bq, c, d; a.u = c00; bq.u = c01; c.u = c10; d.u = c11;
        const __half2 h00 = __float2half2_rn(w00);
        const __half2 h01 = __float2half2_rn(w01);
        const __half2 h10 = __float2half2_rn(w10);
        const __half2 h11 = __float2half2_rn(w11);
        U4H s;
#pragma unroll
        for (int i = 0; i < 4; ++i)
            s.h2[i] = __hfma2(h00, a.h2[i],
                      __hfma2(h01, bq.h2[i],
                      __hfma2(h10, c.h2[i],
                      __hmul2(h11, d.h2[i]))));
        return s.v;
    };

    __syncthreads();   // initial window ready

    // prefetch bookkeeping (k = tid and k = 256+tid of 300 new slots)
    const int pi0 = tid / WCOLS, pj0 = tid - pi0 * WCOLS;
    const int k1  = 256 + tid;
    const int pi1 = k1 / WCOLS, pj1 = k1 - pi1 * WCOLS;
    const bool has1 = (k1 < BR * WCOLS + 256) & (k1 < 300 + 256) & (tid < 44);

#pragma unroll 1
    for (int s = 0; s < TPB; ++s) {
        const int h_base = h_start + BR * s;
        const int h   = h_base + wave;
        const int hb5 = h_base - 5;

        // burst this tile's offset/mask loads (sigmoid + tap-9 pad folded)
        float dyv[2][5], dxv[2][5], msv[2][5];
#pragma unroll
        for (int tile = 0; tile < 2; ++tile) {
            const int wq  = xbase + tile * 32 + lp;
            const int pix = h * W + wq;
#pragma unroll
            for (int m = 0; m < 5; ++m) {
                const int t  = 2 * m + hi;
                const int tt = (t > 8) ? 8 : t;
                const int idx0 = G * KK - 1 - (g * KK + tt);   // flipped tap axis
                dyv[tile][m] = offy[(size_t)idx0 * HW + pix];
                dxv[tile][m] = offx[(size_t)idx0 * HW + pix];
                const float mv = mk[(size_t)(g * KK + tt) * HW + pix];
                float sg = 1.0f / (1.0f + __expf(-mv));
                msv[tile][m] = (t <= 8) ? sg : 0.0f;
            }
        }

        // issue next-4-rows prefetch into regs (latency hides under compute)
        uint4 pf0 = make_uint4(0, 0, 0, 0), pf1 = make_uint4(0, 0, 0, 0);
        int yA = 0, yB = 0;
        bool pv0 = false, pv1 = false;
        if (s < TPB - 1) {
            yA = h_base + 11 + pi0;
            const int gcA = x0base + pj0;
            pv0 = ((unsigned)yA < (unsigned)H) & ((unsigned)gcA < (unsigned)W);
            pf0 = xb[min(max(yA, 0), H - 1) * W + min(max(gcA, 0), W - 1)];
            if (has1) {
                yB = h_base + 11 + pi1;
                const int gcB = x0base + pj1;
                pv1 = ((unsigned)yB < (unsigned)H) & ((unsigned)gcB < (unsigned)W);
                pf1 = xb[min(max(yB, 0), H - 1) * W + min(max(gcB, 0), W - 1)];
            }
        }

        // compute: 10 taps x 2 tiles, MFMA accumulate
        f32x16 acc0 = {};
        f32x16 acc1 = {};
#pragma unroll
        for (int m = 0; m < 5; ++m) {
            const int t  = 2 * m + hi;
            const int tt = (t > 8) ? 8 : t;
            const int ki = (tt >= 3) + (tt >= 6);
            const int kj = tt - 3 * ki;
            const float pyb = (float)(h - PAD + ki);
            const float pxb = (float)(xbase + lp - PAD + kj);
            acc0 = __builtin_amdgcn_mfma_f32_32x32x16_f16(
                afrag[m], sample(hb5, pyb + dyv[0][m], pxb + dxv[0][m], msv[0][m]), acc0, 0, 0, 0);
            acc1 = __builtin_amdgcn_mfma_f32_32x32x16_f16(
                afrag[m], sample(hb5, pyb + dyv[1][m], pxb + 32.0f + dxv[1][m], msv[1][m]), acc1, 0, 0, 0);
        }

        // store: C col = lp, row = (reg&3)+8*(reg>>2)+4*hi -> d = reg+4*hi
#pragma unroll
        for (int tile = 0; tile < 2; ++tile) {
            const int wq = xbase + tile * 32 + lp;
#pragma unroll
            for (int r = 0; r < 4; ++r) {
                const int dd = r + 4 * hi;
                const float v = (tile == 0 ? acc0[r] : acc1[r]) + bias[g * OPG + dd];
                out[((size_t)b * OC + g * OPG + dd) * HW + h * W + wq] = v;
            }
        }

        __syncthreads();   // all reads of old ring rows done
        if (s < TPB - 1) {
            win[(yA & 15) * WCOLS + pj0] = pv0 ? pf0 : make_uint4(0, 0, 0, 0);
            if (has1)
                win[(yB & 15) * WCOLS + pj1] = pv1 ? pf1 : make_uint4(0, 0, 0, 0);
        }
        __syncthreads();   // new rows visible
    }
}

extern "C" void kernel_launch(void* const* d_in, const int* in_sizes, int n_in,
                              void* d_out, int out_size, void* d_ws, size_t ws_size,
                              hipStream_t stream) {
    const float* x      = (const float*)d_in[0];
    const float* offset = (const float*)d_in[1];
    const float* mask   = (const float*)d_in[2];
    const float* weight = (const float*)d_in[3];
    const float* bias   = (const float*)d_in[4];
    float* out = (float*)d_out;

    uint4* xt    = (uint4*)d_ws;                                      // 32 MiB
    uint4* wfrag = (uint4*)((char*)d_ws + (size_t)B * G * HW * 16);   // 40 KiB

    dim3 tgrid(H, G, B);
    transpose_kernel<<<tgrid, dim3(256), 0, stream>>>(x, xt);
    prep_weights<<<dim3(G), dim3(320), 0, stream>>>(weight, wfrag);
    // B*G * (H/16 row-quads) * (W/64 col-blocks) = 2048 blocks
    dcn_kernel<<<dim3(B * G * (H / (BR * TPB)) * (W / BC)), dim3(256), 0, stream>>>(
        xt, wfrag, offset, mask, bias, out);
}